// Round 7
// baseline (51.264 us; speedup 1.0000x reference)
//
#include <hip/hip_runtime.h>
#include <math.h>

#define QN  4
#define CN  256
#define BN  32
#define NN  4096
#define WV  4            // waves per block
#define RPW 32           // rows per wave
#define TR  4            // rows per tile
#define NT  8            // tiles per wave (RPW/TR)
#define SPB 32           // blocks per batch (NN/(WV*RPW))

// Load tile tt's rows into vst regs (lane's float4 = channels lane*4..);
// masked rows (scalar branch on SGPR mbits) become zeros.
#define LOADT(tt) do {                                                   \
    _Pragma("unroll")                                                    \
    for (int j_ = 0; j_ < TR; ++j_) {                                    \
        const int rw_ = (tt) * TR + j_;                                  \
        if (!((mbits >> rw_) & 1ull))                                    \
            vst[j_] = *(const float4*)(hb + (size_t)rw_ * CN + lane * 4);\
        else                                                             \
            vst[j_] = make_float4(0.f, 0.f, 0.f, 0.f);                   \
    }                                                                    \
} while (0)

#define STORET(bp) do {                                                  \
    _Pragma("unroll")                                                    \
    for (int j_ = 0; j_ < TR; ++j_)                                      \
        *(float4*)((bp) + j_ * CN + lane * 4) = vst[j_];                 \
} while (0)

// ---------------------------------------------------------------------------
// Fused single-pass (no-max softmax: |s| bounded ~16, fp32 headroom huge).
// Per wave: 32 rows in 4-row LDS tiles, double-buffered, reg-staged 2-deep.
// Score: 16 lanes/row; reduce-scatter shuffle (5 DS ops per 4 rows).
// Pool: lane owns channels 4*lane..; p broadcast from per-wave LDS pbuf.
// grid = BN*SPB = 1024 blocks x 256 thr; LDS ~33 KB, VGPR<=128 -> 4 blk/CU.
// ---------------------------------------------------------------------------
__global__ __launch_bounds__(256, 4) void k_fused(
    const float* __restrict__ h, const int* __restrict__ mask,
    const float* __restrict__ qr,
    float* __restrict__ P, float* __restrict__ L)
{
    __shared__ float s_stage[WV][2][TR * CN];    // 32 KB (wave-private dbuf)
    __shared__ float s_pbf[WV][TR * QN];         // 256 B
    __shared__ float s_lp[WV][QN];               // 64 B

    const int b    = blockIdx.x >> 5;
    const int sub  = blockIdx.x & (SPB - 1);
    const int w    = threadIdx.x >> 6;
    const int lane = threadIdx.x & 63;
    const int rgrp = lane >> 4;                  // row in tile (0..3)
    const int l15  = lane & 15;
    const int bit0 = l15 & 1, bit1 = (l15 >> 1) & 1;

    const int n0    = (sub * WV + w) * RPW;
    const size_t gn = (size_t)b * NN + n0;
    const float* __restrict__ hb = h + gn * CN;

    // query frags for score channels c = (l15+16k)*4+i  (scale folded in)
    float4 q4[QN][4];
#pragma unroll
    for (int q = 0; q < QN; ++q)
#pragma unroll
        for (int k = 0; k < 4; ++k) {
            float4 t = *(const float4*)(qr + q * CN + (l15 + 16 * k) * 4);
            t.x *= 0.0625f; t.y *= 0.0625f; t.z *= 0.0625f; t.w *= 0.0625f;
            q4[q][k] = t;
        }

    // mask bits for this wave's 32 rows (one ballot, SGPR-resident)
    const unsigned long long mbits =
        __ballot(lane < RPW ? (mask[gn + lane] != 0) : true);

    float* const buf0 = &s_stage[w][0][0];
    float* const buf1 = &s_stage[w][1][0];

    float4 acc[QN];
    float  lsum[QN];
#pragma unroll
    for (int q = 0; q < QN; ++q) {
        acc[q] = make_float4(0.f, 0.f, 0.f, 0.f);
        lsum[q] = 0.f;
    }

    float4 vst[TR];

    // ---- prologue: tile0 -> buf0; preload tile1 into regs ----
    LOADT(0);
    STORET(buf0);
    LOADT(1);

    for (int t = 0; t < NT; ++t) {
        float* const bufc = (t & 1) ? buf1 : buf0;
        float* const bufn = (t & 1) ? buf0 : buf1;

        // ---------- score: 16 lanes/row, rows = rgrp ----------
        {
            const float* rowp = bufc + rgrp * CN;
            float s0 = 0.f, s1 = 0.f, s2 = 0.f, s3 = 0.f;
#pragma unroll
            for (int k = 0; k < 4; ++k) {
                const float4 hv = *(const float4*)(rowp + (l15 + 16 * k) * 4);
                s0 += hv.x * q4[0][k].x + hv.y * q4[0][k].y
                    + hv.z * q4[0][k].z + hv.w * q4[0][k].w;
                s1 += hv.x * q4[1][k].x + hv.y * q4[1][k].y
                    + hv.z * q4[1][k].z + hv.w * q4[1][k].w;
                s2 += hv.x * q4[2][k].x + hv.y * q4[2][k].y
                    + hv.z * q4[2][k].z + hv.w * q4[2][k].w;
                s3 += hv.x * q4[3][k].x + hv.y * q4[3][k].y
                    + hv.z * q4[3][k].z + hv.w * q4[3][k].w;
            }
            // reduce-scatter over 16-lane group: 5 shuffles total.
            // step A (xor1): keep (s0,s1) on even, (s2,s3) on odd
            float t0 = bit0 ? s0 : s2;
            float t1 = bit0 ? s1 : s3;
            float r0 = __shfl_xor(t0, 1, 64);
            float r1 = __shfl_xor(t1, 1, 64);
            float a0 = (bit0 ? s2 : s0) + r0;   // q = 2*bit0
            float a1 = (bit0 ? s3 : s1) + r1;   // q = 2*bit0+1
            // step B (xor2): keep a0 on bit1=0, a1 on bit1=1
            float tb = bit1 ? a0 : a1;
            float rb = __shfl_xor(tb, 2, 64);
            float bq = (bit1 ? a1 : a0) + rb;   // q = 2*bit0 + bit1
            // steps C,D: plain reduce of the single value
            bq += __shfl_xor(bq, 4, 64);
            bq += __shfl_xor(bq, 8, 64);

            const bool mk = ((mbits >> (t * TR + rgrp)) & 1ull) != 0;
            const float p = mk ? 0.f : __expf(bq);
            if (l15 < 4)
                s_pbf[w][rgrp * QN + 2 * bit0 + bit1] = p;
        }

        // ---------- pool: lane owns channels 4*lane.. ----------
#pragma unroll
        for (int r = 0; r < TR; ++r) {
            const float4 pv = *(const float4*)&s_pbf[w][r * QN]; // broadcast
            const float4 hv = *(const float4*)(bufc + r * CN + lane * 4);
            acc[0].x += pv.x * hv.x; acc[0].y += pv.x * hv.y;
            acc[0].z += pv.x * hv.z; acc[0].w += pv.x * hv.w;
            acc[1].x += pv.y * hv.x; acc[1].y += pv.y * hv.y;
            acc[1].z += pv.y * hv.z; acc[1].w += pv.y * hv.w;
            acc[2].x += pv.z * hv.x; acc[2].y += pv.z * hv.y;
            acc[2].z += pv.z * hv.z; acc[2].w += pv.z * hv.w;
            acc[3].x += pv.w * hv.x; acc[3].y += pv.w * hv.y;
            acc[3].z += pv.w * hv.z; acc[3].w += pv.w * hv.w;
            lsum[0] += pv.x; lsum[1] += pv.y;
            lsum[2] += pv.z; lsum[3] += pv.w;
        }

        // ---------- commit tile t+1; issue loads for t+2 ----------
        if (t + 1 < NT) {
            STORET(bufn);              // counted vmcnt wait (compiler)
            if (t + 2 < NT) LOADT(t + 2);
        }
    }

    // ---- epilogue: per-wave partials into own stage region, combine ----
    {
        float* part = &s_stage[w][0][0];          // TR*CN = QN*CN floats
#pragma unroll
        for (int q = 0; q < QN; ++q)
            *(float4*)(part + q * CN + lane * 4) = acc[q];
        if (lane == 0) {
#pragma unroll
            for (int q = 0; q < QN; ++q) s_lp[w][q] = lsum[q];
        }
    }
    __syncthreads();
    {
        const int t = threadIdx.x;                // 256 threads x float4
        float4 o = make_float4(0.f, 0.f, 0.f, 0.f);
#pragma unroll
        for (int ww = 0; ww < WV; ++ww) {
            const float4 v = *(const float4*)(&s_stage[ww][0][0] + t * 4);
            o.x += v.x; o.y += v.y; o.z += v.z; o.w += v.w;
        }
        ((float4*)(P + (size_t)blockIdx.x * (QN * CN)))[t] = o;
        if (t < QN)
            L[blockIdx.x * QN + t] =
                s_lp[0][t] + s_lp[1][t] + s_lp[2][t] + s_lp[3][t];
    }
}

// ---------------------------------------------------------------------------
// Combine SPB block-partials per batch and divide by l (0 if l==0).
// grid = BN*4 blocks x 256 threads; thread = one float of [q][c]; q is
// block-uniform (scalar L loads).
// ---------------------------------------------------------------------------
__global__ __launch_bounds__(256) void k_div(
    const float* __restrict__ P, const float* __restrict__ L,
    float* __restrict__ out)
{
    const int b   = blockIdx.x >> 2;
    const int q   = blockIdx.x & 3;               // quarter == query index
    const int idx = q * CN + threadIdx.x;         // [0, 1024)

    float o = 0.f, l = 0.f;
#pragma unroll 4
    for (int s = 0; s < SPB; ++s) {
        o += P[(size_t)(b * SPB + s) * (QN * CN) + idx];
        l += L[(b * SPB + s) * QN + q];
    }
    out[(size_t)b * (QN * CN) + idx] = (l > 0.f) ? o / l : 0.f;
}

extern "C" void kernel_launch(void* const* d_in, const int* in_sizes, int n_in,
                              void* d_out, int out_size, void* d_ws, size_t ws_size,
                              hipStream_t stream) {
    const float* h    = (const float*)d_in[0];
    const int*   mask = (const int*)d_in[1];
    const float* qr   = (const float*)d_in[2];
    float*       out  = (float*)d_out;

    float* P = (float*)d_ws;                            // [1024][Q*C] = 4 MB
    float* L = P + (size_t)BN * SPB * QN * CN;          // [1024][Q]   = 16 KB

    k_fused<<<BN * SPB, 256, 0, stream>>>(h, mask, qr, P, L);
    k_div  <<<BN * QN, 256, 0, stream>>>(P, L, out);
}

// Round 8
// 28.640 us; speedup vs baseline: 1.7899x; 1.7899x over previous
//
#include <hip/hip_runtime.h>
#include <math.h>

#define QN  4
#define CN  256
#define BN  32
#define NN  4096
#define WV  4            // waves per block
#define RPW 32           // rows per wave
#define TR  4            // rows per tile
#define NT  8            // tiles per wave (RPW/TR)
#define SPB 32           // blocks per batch (NN/(WV*RPW))

// ---------------------------------------------------------------------------
// Fused single-pass (no-max softmax: |s| bounded ~16, fp32 headroom huge).
// Single layout: lane owns channels 4*lane..+3 for score AND pool -> no LDS
// in the main loop. Per 4-row tile: dot partials in regs; 16-value 64-lane
// reduce-scatter (17 shuffles); 1 exp/lane; p broadcast via v_readlane (SGPR)
// into v_fmac. Masked rows: load skipped (stale regs finite), p forced 0.
// grid = BN*SPB = 1024 blocks x 256 thr; ~100 VGPR, 16 KB LDS -> 4 wv/SIMD.
// ---------------------------------------------------------------------------
__global__ __launch_bounds__(256) void k_fused(
    const float* __restrict__ h, const int* __restrict__ mask,
    const float* __restrict__ qr,
    float* __restrict__ P, float* __restrict__ L)
{
    __shared__ float s_part[WV][QN * CN];   // 16 KB, epilogue only
    __shared__ float s_lp[WV][QN];

    const int b    = blockIdx.x >> 5;
    const int sub  = blockIdx.x & (SPB - 1);
    const int w    = threadIdx.x >> 6;
    const int lane = threadIdx.x & 63;

    const int n0    = (sub * WV + w) * RPW;
    const size_t gn = (size_t)b * NN + n0;
    const float* __restrict__ hb = h + gn * CN + lane * 4;

    // lane's 4 channels of each query (scale folded in): 16 VGPRs total
    float4 q4[QN];
#pragma unroll
    for (int q = 0; q < QN; ++q) {
        float4 tq = *(const float4*)(qr + q * CN + lane * 4);
        tq.x *= 0.0625f; tq.y *= 0.0625f; tq.z *= 0.0625f; tq.w *= 0.0625f;
        q4[q] = tq;
    }

    // mask bits for this wave's 32 rows (one ballot, SGPR-resident)
    const unsigned long long mbits =
        __ballot(lane < RPW ? (mask[gn + lane] != 0) : true);

    float4 acc[QN];
#pragma unroll
    for (int q = 0; q < QN; ++q) acc[q] = make_float4(0.f, 0.f, 0.f, 0.f);

    float lheld = 0.f;                   // sum of p for this lane's held (r,q)
    const int rheld = (lane >> 2) & 3;   // row-in-tile whose sum lane holds

    float4 vc[TR], vn[TR];
#pragma unroll
    for (int j = 0; j < TR; ++j) {
        vc[j] = make_float4(0.f, 0.f, 0.f, 0.f);
        vn[j] = make_float4(0.f, 0.f, 0.f, 0.f);
    }
    // prologue: tile 0 (masked rows stay zero)
#pragma unroll
    for (int j = 0; j < TR; ++j)
        if (!((mbits >> j) & 1ull))
            vc[j] = *(const float4*)(hb + (size_t)j * CN);

#pragma unroll
    for (int t = 0; t < NT; ++t) {
        // ---- prefetch tile t+1 (masked rows: keep stale finite regs) ----
        if (t + 1 < NT) {
#pragma unroll
            for (int j = 0; j < TR; ++j) {
                const int rw = (t + 1) * TR + j;
                if (!((mbits >> rw) & 1ull))
                    vn[j] = *(const float4*)(hb + (size_t)rw * CN);
            }
        }

        // ---- dot partials: cur[r*4+q] over lane's 4 channels ----
        float cur[16];
#pragma unroll
        for (int r = 0; r < TR; ++r)
#pragma unroll
            for (int q = 0; q < QN; ++q)
                cur[r * 4 + q] = vc[r].x * q4[q].x + vc[r].y * q4[q].y
                               + vc[r].z * q4[q].z + vc[r].w * q4[q].w;

        // ---- reduce-scatter butterfly: 15 shuffles, value v lands on
        //      lanes with (lane&15)==v; invariant: slot j holds value
        //      v = j*2^(k+1) + (lane mod 2^(k+1)) after step k ----
#pragma unroll
        for (int k = 0; k < 4; ++k) {
            const int  nv = 8 >> k;
            const bool bk = (lane >> k) & 1;
#pragma unroll
            for (int j = 0; j < nv; ++j) {
                const float snd = bk ? cur[2 * j] : cur[2 * j + 1];
                const float rcv = __shfl_xor(snd, 1 << k, 64);
                cur[j] = (bk ? cur[2 * j + 1] : cur[2 * j]) + rcv;
            }
        }
        float sv = cur[0];                       // partial over 16-lane group
        sv += __shfl_xor(sv, 16, 64);
        sv += __shfl_xor(sv, 32, 64);            // full 64-lane sum

        // ---- exp on holder lane; mask -> 0 ----
        const bool  mk = ((mbits >> (t * TR + rheld)) & 1ull) != 0;
        const float pv = mk ? 0.f : __expf(sv);
        lheld += pv;

        // ---- pool: p via readlane (SGPR) * lane's channels ----
#pragma unroll
        for (int r = 0; r < TR; ++r)
#pragma unroll
            for (int q = 0; q < QN; ++q) {
                const float prq = __uint_as_float(
                    __builtin_amdgcn_readlane(__float_as_uint(pv), r * 4 + q));
                acc[q].x += prq * vc[r].x;
                acc[q].y += prq * vc[r].y;
                acc[q].z += prq * vc[r].z;
                acc[q].w += prq * vc[r].w;
            }

        // rotate pipeline
#pragma unroll
        for (int j = 0; j < TR; ++j) vc[j] = vn[j];
    }

    // ---- l[q]: sum lheld over r (lane bits 2,3); lanes 0..3 hold q=lane ----
    float lt = lheld;
    lt += __shfl_xor(lt, 4, 64);
    lt += __shfl_xor(lt, 8, 64);

    // ---- epilogue: block combine via LDS (one-time) ----
#pragma unroll
    for (int q = 0; q < QN; ++q)
        *(float4*)&s_part[w][q * CN + lane * 4] = acc[q];
    if (lane < QN) s_lp[w][lane] = lt;
    __syncthreads();
    {
        const int tt = threadIdx.x;              // 256 threads x float4
        float4 o = make_float4(0.f, 0.f, 0.f, 0.f);
#pragma unroll
        for (int ww = 0; ww < WV; ++ww) {
            const float4 v = *(const float4*)&s_part[ww][tt * 4];
            o.x += v.x; o.y += v.y; o.z += v.z; o.w += v.w;
        }
        ((float4*)(P + (size_t)blockIdx.x * (QN * CN)))[tt] = o;
        if (tt < QN)
            L[blockIdx.x * QN + tt] =
                s_lp[0][tt] + s_lp[1][tt] + s_lp[2][tt] + s_lp[3][tt];
    }
}

// ---------------------------------------------------------------------------
// Combine SPB block-partials per batch and divide by l (0 if l==0).
// grid = BN*QN blocks x 256 threads; q block-uniform (scalar L loads).
// ---------------------------------------------------------------------------
__global__ __launch_bounds__(256) void k_div(
    const float* __restrict__ P, const float* __restrict__ L,
    float* __restrict__ out)
{
    const int b   = blockIdx.x >> 2;
    const int q   = blockIdx.x & 3;
    const int idx = q * CN + threadIdx.x;

    float o = 0.f, l = 0.f;
#pragma unroll 4
    for (int s = 0; s < SPB; ++s) {
        o += P[(size_t)(b * SPB + s) * (QN * CN) + idx];
        l += L[(b * SPB + s) * QN + q];
    }
    out[(size_t)b * (QN * CN) + idx] = (l > 0.f) ? o / l : 0.f;
}

extern "C" void kernel_launch(void* const* d_in, const int* in_sizes, int n_in,
                              void* d_out, int out_size, void* d_ws, size_t ws_size,
                              hipStream_t stream) {
    const float* h    = (const float*)d_in[0];
    const int*   mask = (const int*)d_in[1];
    const float* qr   = (const float*)d_in[2];
    float*       out  = (float*)d_out;

    float* P = (float*)d_ws;                            // [1024][Q*C] = 4 MB
    float* L = P + (size_t)BN * SPB * QN * CN;          // [1024][Q]   = 16 KB

    k_fused<<<BN * SPB, 256, 0, stream>>>(h, mask, qr, P, L);
    k_div  <<<BN * QN, 256, 0, stream>>>(P, L, out);
}

// Round 10
// 24.957 us; speedup vs baseline: 2.0540x; 1.1475x over previous
//
#include <hip/hip_runtime.h>
#include <math.h>

#define QN  4
#define CN  256
#define BN  32
#define NN  4096
#define WV  4            // waves per block
#define RPW 32           // rows per wave
#define SPB 32           // blocks per batch (NN/(WV*RPW))

// Extract up to 4 unmasked-row indices from scalar bitmap um (wave-uniform),
// issue their loads into dst[], record validity nibble in vmdst.
#define EXTRACT_ISSUE(dst, vmdst) do {                                   \
    vmdst = 0u;                                                          \
    _Pragma("unroll")                                                    \
    for (int j_ = 0; j_ < 4; ++j_) {                                     \
        if (um) {                                                        \
            const int r_ = __builtin_ctz(um);                            \
            um &= um - 1u;                                               \
            vmdst |= (1u << j_);                                         \
            dst[j_] = *(const float4*)(hb + (size_t)r_ * CN);            \
        }                                                                \
    }                                                                    \
} while (0)

// ---------------------------------------------------------------------------
// Fused single-pass (no-max softmax: |s| <= ~16, fp32 headroom huge).
// Compacted-row pipeline: iterate ONLY unmasked rows (scalar ctz over the
// ballot bitmap) in tiles of 4, 3-deep register staging -> constant 8 loads
// in flight per wave (Little's-law fix; masked-skip byte saving kept).
// Per tile (identical math to round 8, validated): 16 dot partials,
// reduce-scatter butterfly (17 shuffles), 1 exp, readlane-broadcast pool.
// grid = BN*SPB = 1024 blocks x 256 thr; ~116 VGPR, 16 KB LDS -> 4 wv/SIMD.
// ---------------------------------------------------------------------------
__global__ __launch_bounds__(256) void k_fused(
    const float* __restrict__ h, const int* __restrict__ mask,
    const float* __restrict__ qr,
    float* __restrict__ P, float* __restrict__ Lp)
{
    __shared__ float s_part[WV][QN * CN];   // 16 KB, epilogue only
    __shared__ float s_lp[WV][QN];

    const int b    = blockIdx.x >> 5;
    const int sub  = blockIdx.x & (SPB - 1);
    const int w    = threadIdx.x >> 6;
    const int lane = threadIdx.x & 63;

    const int n0    = (sub * WV + w) * RPW;
    const size_t gn = (size_t)b * NN + n0;
    const float* __restrict__ hb = h + gn * CN + lane * 4;

    // lane's 4 channels of each query (scale folded in): 16 VGPRs
    float4 q4[QN];
#pragma unroll
    for (int q = 0; q < QN; ++q) {
        float4 tq = *(const float4*)(qr + q * CN + lane * 4);
        tq.x *= 0.0625f; tq.y *= 0.0625f; tq.z *= 0.0625f; tq.w *= 0.0625f;
        q4[q] = tq;
    }

    // unmasked-row bitmap for this wave's 32 rows (wave-uniform scalar)
    const unsigned long long mbits =
        __ballot(lane < RPW ? (mask[gn + lane] != 0) : true);
    unsigned um = (unsigned)(~mbits & 0xFFFFFFFFull);
    const int K   = __popc(um);
    const int NTv = (K + 3) >> 2;         // tiles of 4 compacted rows

    float4 acc[QN];
#pragma unroll
    for (int q = 0; q < QN; ++q) acc[q] = make_float4(0.f, 0.f, 0.f, 0.f);

    float lheld = 0.f;                    // p-sum for this lane's held (r,q)
    const int rheld = (lane >> 2) & 3;    // slot whose sum this lane holds

    float4 vc[4], vn[4], vn2[4];
#pragma unroll
    for (int j = 0; j < 4; ++j) {
        vc[j] = make_float4(0.f, 0.f, 0.f, 0.f);
        vn[j] = make_float4(0.f, 0.f, 0.f, 0.f);
        vn2[j] = make_float4(0.f, 0.f, 0.f, 0.f);
    }
    unsigned vm0, vm1, vm2;

    // prologue: stage tiles 0 and 1
    EXTRACT_ISSUE(vc, vm0);
    EXTRACT_ISSUE(vn, vm1);

    for (int t = 0; t < NTv; ++t) {
        // ---- stage tile t+2 (constant-depth pipeline) ----
        if (t + 2 < NTv) EXTRACT_ISSUE(vn2, vm2);
        else             vm2 = 0u;

        // ---- dot partials: cur[r*4+q] over lane's 4 channels ----
        float cur[16];
#pragma unroll
        for (int r = 0; r < 4; ++r)
#pragma unroll
            for (int q = 0; q < QN; ++q)
                cur[r * 4 + q] = vc[r].x * q4[q].x + vc[r].y * q4[q].y
                               + vc[r].z * q4[q].z + vc[r].w * q4[q].w;

        // ---- reduce-scatter butterfly: value v lands on (lane&15)==v ----
#pragma unroll
        for (int k = 0; k < 4; ++k) {
            const int  nv = 8 >> k;
            const bool bk = (lane >> k) & 1;
#pragma unroll
            for (int j = 0; j < nv; ++j) {
                const float snd = bk ? cur[2 * j] : cur[2 * j + 1];
                const float rcv = __shfl_xor(snd, 1 << k, 64);
                cur[j] = (bk ? cur[2 * j + 1] : cur[2 * j]) + rcv;
            }
        }
        float sv = cur[0];                       // partial over 16-lane group
        sv += __shfl_xor(sv, 16, 64);
        sv += __shfl_xor(sv, 32, 64);            // full 64-lane sum

        // ---- exp on holder lane; invalid tail slot -> 0 ----
        const bool  ok = (vm0 >> rheld) & 1u;
        const float pv = ok ? __expf(sv) : 0.f;
        lheld += pv;

        // ---- pool: p via readlane (SGPR) * lane's channels ----
#pragma unroll
        for (int r = 0; r < 4; ++r)
#pragma unroll
            for (int q = 0; q < QN; ++q) {
                const float prq = __uint_as_float(
                    __builtin_amdgcn_readlane(__float_as_uint(pv), r * 4 + q));
                acc[q].x += prq * vc[r].x;
                acc[q].y += prq * vc[r].y;
                acc[q].z += prq * vc[r].z;
                acc[q].w += prq * vc[r].w;
            }

        // rotate pipeline
#pragma unroll
        for (int j = 0; j < 4; ++j) { vc[j] = vn[j]; vn[j] = vn2[j]; }
        vm0 = vm1; vm1 = vm2;
    }

    // ---- l[q]: fold slots (lane bits 2,3); lanes 0..3 hold q=lane ----
    float lt = lheld;
    lt += __shfl_xor(lt, 4, 64);
    lt += __shfl_xor(lt, 8, 64);

    // ---- block combine via LDS; write per-block partial ----
#pragma unroll
    for (int q = 0; q < QN; ++q)
        *(float4*)&s_part[w][q * CN + lane * 4] = acc[q];
    if (lane < QN) s_lp[w][lane] = lt;
    __syncthreads();
    {
        const int tt = threadIdx.x;              // 256 threads x float4
        float4 o = make_float4(0.f, 0.f, 0.f, 0.f);
#pragma unroll
        for (int ww = 0; ww < WV; ++ww) {
            const float4 v = *(const float4*)&s_part[ww][tt * 4];
            o.x += v.x; o.y += v.y; o.z += v.z; o.w += v.w;
        }
        ((float4*)(P + (size_t)blockIdx.x * (QN * CN)))[tt] = o;
        if (tt < QN)
            Lp[blockIdx.x * QN + tt] =
                s_lp[0][tt] + s_lp[1][tt] + s_lp[2][tt] + s_lp[3][tt];
    }
}

// ---------------------------------------------------------------------------
// Combine SPB block-partials per batch and divide by l (0 if l==0).
// grid = BN*QN blocks x 256 threads; q block-uniform (scalar L loads).
// ---------------------------------------------------------------------------
__global__ __launch_bounds__(256) void k_div(
    const float* __restrict__ P, const float* __restrict__ Lp,
    float* __restrict__ out)
{
    const int b   = blockIdx.x >> 2;
    const int q   = blockIdx.x & 3;
    const int idx = q * CN + threadIdx.x;

    float o = 0.f, l = 0.f;
#pragma unroll 4
    for (int s = 0; s < SPB; ++s) {
        o += P[(size_t)(b * SPB + s) * (QN * CN) + idx];
        l += Lp[(b * SPB + s) * QN + q];
    }
    out[(size_t)b * (QN * CN) + idx] = (l > 0.f) ? o / l : 0.f;
}

extern "C" void kernel_launch(void* const* d_in, const int* in_sizes, int n_in,
                              void* d_out, int out_size, void* d_ws, size_t ws_size,
                              hipStream_t stream) {
    const float* h    = (const float*)d_in[0];
    const int*   mask = (const int*)d_in[1];
    const float* qr   = (const float*)d_in[2];
    float*       out  = (float*)d_out;

    float* P  = (float*)d_ws;                           // [1024][Q*C] = 4 MB
    float* Lp = P + (size_t)BN * SPB * QN * CN;         // [1024][Q]   = 16 KB

    k_fused<<<BN * SPB, 256, 0, stream>>>(h, mask, qr, P, Lp);
    k_div  <<<BN * QN, 256, 0, stream>>>(P, Lp, out);
}

// Round 11
// 24.165 us; speedup vs baseline: 2.1214x; 1.0328x over previous
//
#include <hip/hip_runtime.h>
#include <math.h>

#define QN  4
#define CN  256
#define BN  32
#define NN  4096
#define WV  4            // waves per block
#define RPW 32           // rows per wave
#define SPB 32           // blocks per batch (NN/(WV*RPW))

// Issue 4 row-loads for the next compacted tile into dst[] (UNCONDITIONAL:
// exhausted slots reload row 0 so the waitcnt scoreboard stays static);
// validity nibble in vmdst gates their contribution later.
#define EXTRACT_ISSUE(dst, vmdst) do {                                   \
    vmdst = 0u;                                                          \
    _Pragma("unroll")                                                    \
    for (int j_ = 0; j_ < 4; ++j_) {                                     \
        const int r_ = um ? (int)__builtin_ctz(um) : 0;                  \
        if (um) vmdst |= (1u << j_);                                     \
        um &= um - 1u;                                                   \
        dst[j_] = *(const float4*)(hb + (size_t)r_ * CN);                \
    }                                                                    \
} while (0)

// Compute one 4-row tile from buffer bf with validity nibble vm:
// 16 dot partials -> reduce-scatter butterfly -> 1 exp -> readlane pool.
#define COMPUTE(bf, vm) do {                                             \
    float cur[16];                                                       \
    _Pragma("unroll")                                                    \
    for (int r_ = 0; r_ < 4; ++r_)                                       \
        _Pragma("unroll")                                                \
        for (int q_ = 0; q_ < QN; ++q_)                                  \
            cur[r_ * 4 + q_] = bf[r_].x * q4[q_].x + bf[r_].y * q4[q_].y \
                             + bf[r_].z * q4[q_].z + bf[r_].w * q4[q_].w;\
    _Pragma("unroll")                                                    \
    for (int k_ = 0; k_ < 4; ++k_) {                                     \
        const int  nv_ = 8 >> k_;                                        \
        const bool bk_ = (lane >> k_) & 1;                               \
        _Pragma("unroll")                                                \
        for (int j_ = 0; j_ < nv_; ++j_) {                               \
            const float snd_ = bk_ ? cur[2 * j_] : cur[2 * j_ + 1];      \
            const float rcv_ = __shfl_xor(snd_, 1 << k_, 64);            \
            cur[j_] = (bk_ ? cur[2 * j_ + 1] : cur[2 * j_]) + rcv_;      \
        }                                                                \
    }                                                                    \
    float sv_ = cur[0];                                                  \
    sv_ += __shfl_xor(sv_, 16, 64);                                      \
    sv_ += __shfl_xor(sv_, 32, 64);                                      \
    const bool  ok_ = ((vm) >> rheld) & 1u;                              \
    const float pv_ = ok_ ? __expf(sv_) : 0.f;                           \
    lheld += pv_;                                                        \
    _Pragma("unroll")                                                    \
    for (int r_ = 0; r_ < 4; ++r_)                                       \
        _Pragma("unroll")                                                \
        for (int q_ = 0; q_ < QN; ++q_) {                                \
            const float prq_ = __uint_as_float(__builtin_amdgcn_readlane(\
                __float_as_uint(pv_), r_ * 4 + q_));                     \
            acc[q_].x += prq_ * bf[r_].x;                                \
            acc[q_].y += prq_ * bf[r_].y;                                \
            acc[q_].z += prq_ * bf[r_].z;                                \
            acc[q_].w += prq_ * bf[r_].w;                                \
        }                                                                \
} while (0)

// ---------------------------------------------------------------------------
// Fused single-pass (no-max softmax: |s| <= ~16, fp32 headroom huge).
// Compacted-row stream in 4-row tiles; MODULO-3 software pipeline with three
// static buffers rotating ROLES (no register copies -> SSA renaming -> the
// compiler emits counted vmcnt waits; constant 8 rows of loads in flight).
// grid = BN*SPB = 1024 blocks x 256 thr; ~120 VGPR, 16 KB LDS -> 4 wv/SIMD.
// ---------------------------------------------------------------------------
__global__ __launch_bounds__(256) void k_fused(
    const float* __restrict__ h, const int* __restrict__ mask,
    const float* __restrict__ qr,
    float* __restrict__ P, float* __restrict__ Lp)
{
    __shared__ float s_part[WV][QN * CN];   // 16 KB, epilogue only
    __shared__ float s_lp[WV][QN];

    const int b    = blockIdx.x >> 5;
    const int sub  = blockIdx.x & (SPB - 1);
    const int w    = threadIdx.x >> 6;
    const int lane = threadIdx.x & 63;

    const int n0    = (sub * WV + w) * RPW;
    const size_t gn = (size_t)b * NN + n0;
    const float* __restrict__ hb = h + gn * CN + lane * 4;

    // lane's 4 channels of each query (scale folded in): 16 VGPRs
    float4 q4[QN];
#pragma unroll
    for (int q = 0; q < QN; ++q) {
        float4 tq = *(const float4*)(qr + q * CN + lane * 4);
        tq.x *= 0.0625f; tq.y *= 0.0625f; tq.z *= 0.0625f; tq.w *= 0.0625f;
        q4[q] = tq;
    }

    // unmasked-row bitmap for this wave's 32 rows (wave-uniform scalar)
    const unsigned long long mbits =
        __ballot(lane < RPW ? (mask[gn + lane] != 0) : true);
    unsigned um = (unsigned)(~mbits & 0xFFFFFFFFull);
    const int K   = __popc(um);
    const int NTv = (K + 3) >> 2;         // tiles of 4 compacted rows

    float4 acc[QN];
#pragma unroll
    for (int q = 0; q < QN; ++q) acc[q] = make_float4(0.f, 0.f, 0.f, 0.f);

    float lheld = 0.f;                    // p-sum for this lane's held (r,q)
    const int rheld = (lane >> 2) & 3;    // slot whose sum this lane holds

    float4 va[4], vb[4], vz[4];
    unsigned vmA, vmB, vmZ;

    if (NTv > 0) {
        // prologue: tiles 0 and 1
        EXTRACT_ISSUE(va, vmA);
        EXTRACT_ISSUE(vb, vmB);

        int t = 0;
        while (true) {
            EXTRACT_ISSUE(vz, vmZ);       // tile t+2
            COMPUTE(va, vmA);             // tile t
            if (++t >= NTv) break;

            EXTRACT_ISSUE(va, vmA);       // tile t+2
            COMPUTE(vb, vmB);             // tile t+1
            if (++t >= NTv) break;

            EXTRACT_ISSUE(vb, vmB);       // tile t+2
            COMPUTE(vz, vmZ);             // tile t+2 of prev group
            if (++t >= NTv) break;
        }
    }

    // ---- l[q]: fold slots (lane bits 2,3); lanes 0..3 hold q=lane ----
    float lt = lheld;
    lt += __shfl_xor(lt, 4, 64);
    lt += __shfl_xor(lt, 8, 64);

    // ---- block combine via LDS; write per-block partial ----
#pragma unroll
    for (int q = 0; q < QN; ++q)
        *(float4*)&s_part[w][q * CN + lane * 4] = acc[q];
    if (lane < QN) s_lp[w][lane] = lt;
    __syncthreads();
    {
        const int tt = threadIdx.x;              // 256 threads x float4
        float4 o = make_float4(0.f, 0.f, 0.f, 0.f);
#pragma unroll
        for (int ww = 0; ww < WV; ++ww) {
            const float4 v = *(const float4*)&s_part[ww][tt * 4];
            o.x += v.x; o.y += v.y; o.z += v.z; o.w += v.w;
        }
        ((float4*)(P + (size_t)blockIdx.x * (QN * CN)))[tt] = o;
        if (tt < QN)
            Lp[blockIdx.x * QN + tt] =
                s_lp[0][tt] + s_lp[1][tt] + s_lp[2][tt] + s_lp[3][tt];
    }
}

// ---------------------------------------------------------------------------
// Combine SPB block-partials per batch and divide by l (0 if l==0).
// grid = BN*QN blocks x 256 threads; q block-uniform (scalar L loads).
// ---------------------------------------------------------------------------
__global__ __launch_bounds__(256) void k_div(
    const float* __restrict__ P, const float* __restrict__ Lp,
    float* __restrict__ out)
{
    const int b   = blockIdx.x >> 2;
    const int q   = blockIdx.x & 3;
    const int idx = q * CN + threadIdx.x;

    float o = 0.f, l = 0.f;
#pragma unroll 4
    for (int s = 0; s < SPB; ++s) {
        o += P[(size_t)(b * SPB + s) * (QN * CN) + idx];
        l += Lp[(b * SPB + s) * QN + q];
    }
    out[(size_t)b * (QN * CN) + idx] = (l > 0.f) ? o / l : 0.f;
}

extern "C" void kernel_launch(void* const* d_in, const int* in_sizes, int n_in,
                              void* d_out, int out_size, void* d_ws, size_t ws_size,
                              hipStream_t stream) {
    const float* h    = (const float*)d_in[0];
    const int*   mask = (const int*)d_in[1];
    const float* qr   = (const float*)d_in[2];
    float*       out  = (float*)d_out;

    float* P  = (float*)d_ws;                           // [1024][Q*C] = 4 MB
    float* Lp = P + (size_t)BN * SPB * QN * CN;         // [1024][Q]   = 16 KB

    k_fused<<<BN * SPB, 256, 0, stream>>>(h, mask, qr, P, Lp);
    k_div  <<<BN * QN, 256, 0, stream>>>(P, Lp, out);
}